// Round 15
// baseline (33.321 us; speedup 1.0000x reference)
//
#include <hip/hip_runtime.h>
#include <hip/hip_bf16.h>
#include <math.h>

#define N_DIM 1024
#define C_DIM 256
#define CN (C_DIM * N_DIM)
#define TOT (8 * CN)
#define BN_EPS 1e-5f
#define SCALE 0.1f

typedef short short8 __attribute__((ext_vector_type(8)));
typedef float f32x4 __attribute__((ext_vector_type(4)));

__device__ __forceinline__ float mspike(float x) {
    return rintf(fminf(fmaxf(x, 0.f), 4.f)) * 0.25f;
}
__device__ __forceinline__ unsigned short bfbits(float x) {
    __hip_bfloat16 h = __float2bfloat16(x);
    return *reinterpret_cast<unsigned short*>(&h);
}
__device__ __forceinline__ f32x4 mfma16(short8 a, short8 b, f32x4 c) {
    return __builtin_amdgcn_mfma_f32_16x16x32_bf16(a, b, c, 0, 0, 0);
}
__device__ __forceinline__ void async16(void* lds, const void* g) {
    __builtin_amdgcn_global_load_lds(
        (const __attribute__((address_space(1))) void*)g,
        (__attribute__((address_space(3))) void*)lds, 16, 0, 0);
}

// ==== K1 (512 blocks): add+spike+transpose + 2 weight rows + zero kvt ======
__global__ __launch_bounds__(256) void prep_spike_kernel(
    const float* __restrict__ q, const float* __restrict__ qp,
    const float* __restrict__ w, const float* __restrict__ cb,
    const float* __restrict__ g, const float* __restrict__ bet,
    const float* __restrict__ mn, const float* __restrict__ vr,
    unsigned short* __restrict__ sxT, unsigned short* __restrict__ whl,
    float* __restrict__ bninv, float* __restrict__ bnsh,
    float* __restrict__ kvt) {
    int logical = ((blockIdx.x & 7) << 6) + (blockIdx.x >> 3);
    int t = threadIdx.x;
    if (blockIdx.x < 64) {
        float4 z4 = make_float4(0.f, 0.f, 0.f, 0.f);
        ((float4*)kvt)[blockIdx.x * 256 + t] = z4;
    }
    __shared__ float ld[64][65];
    {
        int tb = logical >> 6, u = logical & 63;
        int c0 = (u >> 4) * 64, n0 = (u & 15) * 64;
        int cl = t >> 4, nl = (t & 15) * 4;
        size_t base = (size_t)tb * CN;
#pragma unroll
        for (int r = 0; r < 4; ++r) {
            int c = cl + r * 16;
            size_t off = base + (size_t)(c0 + c) * N_DIM + n0 + nl;
            float4 a = *(const float4*)&q[off];
            float4 b = *(const float4*)&qp[off];
            ld[c][nl] = mspike(a.x + b.x);
            ld[c][nl + 1] = mspike(a.y + b.y);
            ld[c][nl + 2] = mspike(a.z + b.z);
            ld[c][nl + 3] = mspike(a.w + b.w);
        }
        __syncthreads();
        int nl2 = t >> 2, cg2 = (t & 3) * 16;
        size_t ob = base + (size_t)(n0 + nl2) * C_DIM + c0 + cg2;
        short8 v0, v1;
#pragma unroll
        for (int j = 0; j < 8; ++j) {
            v0[j] = (short)bfbits(ld[cg2 + j][nl2]);
            v1[j] = (short)bfbits(ld[cg2 + 8 + j][nl2]);
        }
        *(short8*)&sxT[ob] = v0;
        *(short8*)&sxT[ob + 8] = v1;
    }
    {
        int row = 2 * logical + (t >> 7);
        int tl = t & 127;
        float2 wv = *(const float2*)&w[(size_t)row * 256 + tl * 2];
        __hip_bfloat16 h0 = __float2bfloat16(wv.x);
        __hip_bfloat16 h1 = __float2bfloat16(wv.y);
        __hip_bfloat16 l0 = __float2bfloat16(wv.x - __bfloat162float(h0));
        __hip_bfloat16 l1 = __float2bfloat16(wv.y - __bfloat162float(h1));
        size_t base = (size_t)row * 512;
        *(ushort2*)&whl[base + tl * 2] =
            make_ushort2(*(unsigned short*)&h0, *(unsigned short*)&h1);
        *(ushort2*)&whl[base + 256 + tl * 2] =
            make_ushort2(*(unsigned short*)&l0, *(unsigned short*)&l1);
        if (tl == 0) {
            float inv = g[row] / sqrtf(vr[row] + BN_EPS);
            bninv[row] = inv;
            bnsh[row] = (cb[row] - mn[row]) * inv + bet[row];
        }
    }
}

// ==== K2 (512 blocks): q conv (u<32) | fused kv conv + kTv f32 atomics =====
__global__ __launch_bounds__(256, 2) void conv_qkv_kernel(
    const unsigned short* __restrict__ whl,
    const unsigned short* __restrict__ actT,
    const float* __restrict__ bninv, const float* __restrict__ bnsh,
    unsigned short* __restrict__ dq, float* __restrict__ kvt) {
    __shared__ char lds[49152];
    int bz = blockIdx.x;
    int tb = bz & 7, u = bz >> 3;
    const int tid = threadIdx.x, lane = tid & 63, wid = tid >> 6;
    const int wm = wid >> 1, wn = wid & 1;
    const int l15 = lane & 15, l4 = lane >> 4;
    const unsigned short* abase = actT + (size_t)tb * CN;
    f32x4 z = {0.f, 0.f, 0.f, 0.f};

    if (u < 32) {
        int m0 = (u >> 4) * 128, n0 = (u & 15) * 64;
        short* Bp = (short*)lds;
        short* Aq = (short*)(lds + 32768);
        const unsigned short* pa[4];
        const unsigned short* pb[2];
#pragma unroll
        for (int c = 0; c < 4; ++c) {
            int s = c * 256 + tid, row = s >> 3, gsw = ((s & 7) ^ (row & 7)) * 8;
            pa[c] = whl + (size_t)(m0 + row) * 512 + gsw;
        }
#pragma unroll
        for (int c = 0; c < 2; ++c) {
            int s = c * 256 + tid, row = s >> 3, gsw = ((s & 7) ^ (row & 7)) * 8;
            pb[c] = abase + (size_t)(n0 + row) * 256 + gsw;
        }
        f32x4 acc[4][2];
#pragma unroll
        for (int i = 0; i < 4; ++i) { acc[i][0] = z; acc[i][1] = z; }
#pragma unroll
        for (int p = 0; p < 4; ++p)
#pragma unroll
            for (int c = 0; c < 2; ++c)
                async16(&Bp[p * 4096 + (c * 256 + tid) * 8], pb[c] + p * 64);
#pragma unroll
        for (int c = 0; c < 4; ++c)
            async16(&Aq[(c * 256 + tid) * 8], pa[c]);
        __syncthreads();
        for (int kt = 0; kt < 8; ++kt) {
            const char* bbase = (const char*)(Bp + (kt & 3) * 4096);
#pragma unroll
            for (int kk = 0; kk < 2; ++kk) {
                short8 af[4], bf[2];
#pragma unroll
                for (int f = 0; f < 4; ++f) {
                    int rowa = wm * 64 + f * 16 + l15;
                    int ka = ((kk * 4 + l4) ^ (rowa & 7)) << 4;
                    af[f] = *(const short8*)((const char*)Aq + rowa * 128 + ka);
                }
#pragma unroll
                for (int f = 0; f < 2; ++f) {
                    int rowb = wn * 32 + f * 16 + l15;
                    int kb2 = ((kk * 4 + l4) ^ (rowb & 7)) << 4;
                    bf[f] = *(const short8*)(bbase + rowb * 128 + kb2);
                }
#pragma unroll
                for (int i = 0; i < 4; ++i) {
                    acc[i][0] = mfma16(af[i], bf[0], acc[i][0]);
                    acc[i][1] = mfma16(af[i], bf[1], acc[i][1]);
                }
            }
            __syncthreads();
            if (kt < 7) {
#pragma unroll
                for (int c = 0; c < 4; ++c)
                    async16(&Aq[(c * 256 + tid) * 8], pa[c] + (kt + 1) * 64);
                __syncthreads();
            }
        }
#pragma unroll
        for (int i = 0; i < 4; ++i) {
            int cb4 = m0 + wm * 64 + i * 16 + l4 * 4;
            float4 inv = *(const float4*)&bninv[cb4];
            float4 sh = *(const float4*)&bnsh[cb4];
#pragma unroll
            for (int j = 0; j < 2; ++j) {
                int n = n0 + wn * 32 + j * 16 + l15;
                f32x4 a = acc[i][j];
                ushort4 u4;
                u4.x = bfbits(mspike(a[0] * inv.x + sh.x));
                u4.y = bfbits(mspike(a[1] * inv.y + sh.y));
                u4.z = bfbits(mspike(a[2] * inv.z + sh.z));
                u4.w = bfbits(mspike(a[3] * inv.w + sh.w));
                *(ushort4*)&dq[(size_t)tb * CN + (size_t)n * C_DIM + cb4] = u4;
            }
        }
    } else {
        int v = u - 32;
        int m0 = (v >> 2) * 128, c0t = v & 3, n0 = c0t * 64;
        short* At = (short*)lds;
        char* Bb = lds + 16384;
        const unsigned short* pa[4];
        const unsigned short* pw[4][2];
#pragma unroll
        for (int c = 0; c < 4; ++c) {
            int s = c * 256 + tid, row = s >> 3, gsw = ((s & 7) ^ (row & 7)) * 8;
            pa[c] = abase + (size_t)(m0 + row) * 256 + gsw;
        }
#pragma unroll
        for (int c = 0; c < 2; ++c) {
            int s = c * 256 + tid, row = s >> 3, gsw = ((s & 7) ^ (row & 7)) * 8;
            const unsigned short* k_base = whl + 131072 + (size_t)(n0 + row) * 512 + gsw;
            const unsigned short* v_base = whl + 2 * 131072 + (size_t)(n0 + row) * 512 + gsw;
            pw[0][c] = k_base;
            pw[1][c] = k_base + 256;
            pw[2][c] = v_base;
            pw[3][c] = v_base + 256;
        }
        f32x4 kacc[4][2], vacc[4][2];
#pragma unroll
        for (int i = 0; i < 4; ++i) {
            kacc[i][0] = z; kacc[i][1] = z; vacc[i][0] = z; vacc[i][1] = z;
        }
        for (int p = 0; p < 4; ++p) {
#pragma unroll
            for (int c = 0; c < 4; ++c)
                async16(&At[(c * 256 + tid) * 8], pa[c] + p * 64);
#pragma unroll
            for (int b = 0; b < 4; ++b)
#pragma unroll
                for (int c = 0; c < 2; ++c)
                    async16(Bb + b * 8192 + (c * 256 + tid) * 16, pw[b][c] + p * 64);
            __syncthreads();
#pragma unroll
            for (int kk = 0; kk < 2; ++kk) {
                short8 af[4];
#pragma unroll
                for (int f = 0; f < 4; ++f) {
                    int rowa = wm * 64 + f * 16 + l15;
                    int ka = ((kk * 4 + l4) ^ (rowa & 7)) << 4;
                    af[f] = *(const short8*)((const char*)At + rowa * 128 + ka);
                }
                short8 bf[4][2];
#pragma unroll
                for (int b = 0; b < 4; ++b)
#pragma unroll
                    for (int f = 0; f < 2; ++f) {
                        int rowb = wn * 32 + f * 16 + l15;
                        int kb2 = ((kk * 4 + l4) ^ (rowb & 7)) << 4;
                        bf[b][f] = *(const short8*)(Bb + b * 8192 + rowb * 128 + kb2);
                    }
#pragma unroll
                for (int i = 0; i < 4; ++i) {
#pragma unroll
                    for (int f = 0; f < 2; ++f) {
                        kacc[i][f] = mfma16(af[i], bf[0][f], kacc[i][f]);
                        kacc[i][f] = mfma16(af[i], bf[1][f], kacc[i][f]);
                        vacc[i][f] = mfma16(af[i], bf[2][f], vacc[i][f]);
                        vacc[i][f] = mfma16(af[i], bf[3][f], vacc[i][f]);
                    }
                }
            }
            __syncthreads();
        }
        char* kT = lds;
        char* vT = lds + 17408;
#pragma unroll
        for (int j = 0; j < 2; ++j) {
            int cwi = wn * 32 + j * 16 + l15;
            int ck = 256 + n0 + cwi;
            int cv = 512 + n0 + cwi;
            float kinv = bninv[ck], ksh = bnsh[ck];
            float vinv = bninv[cv], vsh = bnsh[cv];
#pragma unroll
            for (int i = 0; i < 4; ++i) {
                int nb = wm * 64 + i * 16 + l4 * 4;
                f32x4 ka = kacc[i][j], va = vacc[i][j];
                ushort4 ku, vu;
                ku.x = bfbits(mspike(ka[0] * kinv + ksh));
                ku.y = bfbits(mspike(ka[1] * kinv + ksh));
                ku.z = bfbits(mspike(ka[2] * kinv + ksh));
                ku.w = bfbits(mspike(ka[3] * kinv + ksh));
                vu.x = bfbits(mspike(va[0] * vinv + vsh));
                vu.y = bfbits(mspike(va[1] * vinv + vsh));
                vu.z = bfbits(mspike(va[2] * vinv + vsh));
                vu.w = bfbits(mspike(va[3] * vinv + vsh));
                *(ushort4*)(kT + cwi * 272 + nb * 2) = ku;
                *(ushort4*)(vT + cwi * 272 + nb * 2) = vu;
            }
        }
        __syncthreads();
        f32x4 pk[2];
        pk[0] = z; pk[1] = z;
#pragma unroll
        for (int ks = 0; ks < 4; ++ks) {
            short8 a = *(const short8*)(vT + (wn * 32 + wm * 16 + l15) * 272 +
                                        ks * 64 + l4 * 16);
#pragma unroll
            for (int j = 0; j < 2; ++j) {
                short8 b = *(const short8*)(kT + (wn * 32 + j * 16 + l15) * 272 +
                                            ks * 64 + l4 * 16);
                pk[j] = mfma16(a, b, pk[j]);
            }
        }
        int h = c0t * 2 + wn;
        float* dst = kvt + (((size_t)tb * 8 + h) * 32) * 32;
#pragma unroll
        for (int j = 0; j < 2; ++j)
#pragma unroll
            for (int r = 0; r < 4; ++r) {
                int d2 = wm * 16 + l4 * 4 + r, d1 = j * 16 + l15;
                atomicAdd(&dst[(size_t)d2 * 32 + d1], pk[j][r]);
            }
    }
}

// ==== K3 (512 blocks, 32 n-rows): kvt split + ov + conv3 + residual ========
// block: tb = bz&7, u = bz>>3 (0..63): m0 = (u>>1)*32, cop = u&1
__global__ __launch_bounds__(256, 2) void ov_conv_kernel(
    const unsigned short* __restrict__ whl,
    const unsigned short* __restrict__ sqT,
    const float* __restrict__ kvtg,
    const float* __restrict__ bninv, const float* __restrict__ bnsh,
    const float* __restrict__ query, const float* __restrict__ qpos,
    float* __restrict__ outf) {
    __shared__ char lds[49152];
    char* kvt = lds;            // 256 rows x 128 B (32 KB), XOR-swizzled
    char* oT = lds + 32768;     // 32 rows (n) x 512 B (16 KB), XOR-swizzled
    int bz = blockIdx.x;
    int tb = bz & 7, u = bz >> 3;
    int m0 = (u >> 1) * 32, cop = u & 1;
    const int tid = threadIdx.x, lane = tid & 63, w = tid >> 6;
    const int l15 = lane & 15, l4 = lane >> 4;
    f32x4 z = {0.f, 0.f, 0.f, 0.f};

    // phase A: read exact kTv (32 KB, L2-resident), hi/lo split -> kvt LDS
    {
        int h = tid >> 5, d2 = tid & 31;
        const float* src = kvtg + (((size_t)tb * 8 + h) * 32 + d2) * 32;
        unsigned short hl[64];
#pragma unroll
        for (int c = 0; c < 8; ++c) {
            float4 v4 = *(const float4*)&src[c * 4];
            float xs[4] = {v4.x, v4.y, v4.z, v4.w};
#pragma unroll
            for (int e = 0; e < 4; ++e) {
                int d = c * 4 + e;
                unsigned short hi = bfbits(xs[e]);
                __hip_bfloat16 hb = *(__hip_bfloat16*)&hi;
                hl[d] = hi;
                hl[32 + d] = bfbits(xs[e] - __bfloat162float(hb));
            }
        }
        int row = tid;
#pragma unroll
        for (int c = 0; c < 8; ++c) {
            short8 v8;
#pragma unroll
            for (int e = 0; e < 8; ++e) v8[e] = (short)hl[c * 8 + e];
            *(short8*)(kvt + row * 128 + ((c * 16) ^ ((row & 7) << 4))) = v8;
        }
    }
    __syncthreads();

    // phase B: o for 32 rows; wave: nh = w>>1 (16-row half), hh = (w&1)*4
    {
        int nh = w >> 1, hh = (w & 1) * 4;
        f32x4 oacc[4][2];
#pragma unroll
        for (int h = 0; h < 4; ++h) { oacc[h][0] = z; oacc[h][1] = z; }
        const unsigned short* qb = sqT + (size_t)tb * CN;
        int n = m0 + nh * 16 + l15;
#pragma unroll
        for (int h = 0; h < 4; ++h) {
            int hreal = hh + h;
            short8 aq = *(const short8*)&qb[(size_t)n * C_DIM + hreal * 32 + l4 * 8];
#pragma unroll
            for (int j = 0; j < 2; ++j) {
                int row = hreal * 32 + j * 16 + l15;
                short8 bhi = *(const short8*)(kvt + row * 128 +
                                              ((l4 * 16) ^ ((row & 7) << 4)));
                short8 blo = *(const short8*)(kvt + row * 128 +
                                              ((64 + l4 * 16) ^ ((row & 7) << 4)));
                oacc[h][j] = mfma16(aq, bhi, oacc[h][j]);
                oacc[h][j] = mfma16(aq, blo, oacc[h][j]);
            }
        }
#pragma unroll
        for (int h = 0; h < 4; ++h)
#pragma unroll
            for (int j = 0; j < 2; ++j)
#pragma unroll
                for (int r = 0; r < 4; ++r) {
                    int nl = nh * 16 + l4 * 4 + r;
                    int c = (hh + h) * 32 + j * 16 + l15;
                    unsigned short sv = bfbits(mspike(SCALE * oacc[h][j][r]));
                    *(unsigned short*)(oT + nl * 512 +
                                       ((c * 2) ^ ((nl & 7) << 4))) = sv;
                }
    }
    __syncthreads();

    // phase C: out[32n][128c] = o @ W3hi^T (K=256) + BN + (q+qp) residual
    {
        f32x4 acc[2][2];
        acc[0][0] = z; acc[0][1] = z; acc[1][0] = z; acc[1][1] = z;
        const unsigned short* w3 = whl + 3 * 131072;
#pragma unroll
        for (int kc = 0; kc < 8; ++kc) {
            short8 af[2], bf[2];
#pragma unroll
            for (int i = 0; i < 2; ++i) {
                int n = i * 16 + l15;
                af[i] = *(const short8*)(oT + n * 512 +
                                         ((kc * 64 + l4 * 16) ^ ((n & 7) << 4)));
            }
#pragma unroll
            for (int j = 0; j < 2; ++j) {
                int crow = cop * 128 + (w * 2 + j) * 16 + l15;
                bf[j] = *(const short8*)&w3[(size_t)crow * 512 + kc * 32 + l4 * 8];
            }
#pragma unroll
            for (int i = 0; i < 2; ++i) {
                acc[i][0] = mfma16(af[i], bf[0], acc[i][0]);
                acc[i][1] = mfma16(af[i], bf[1], acc[i][1]);
            }
        }
#pragma unroll
        for (int j = 0; j < 2; ++j) {
            int c = cop * 128 + (w * 2 + j) * 16 + l15;
            float inv = bninv[768 + c], sh = bnsh[768 + c];
#pragma unroll
            for (int i = 0; i < 2; ++i) {
                int nb = m0 + i * 16 + l4 * 4;
                size_t off = (size_t)tb * CN + (size_t)c * N_DIM + nb;
                f32x4 a = acc[i][j];
                float4 t4 = *(const float4*)&query[off];
                float4 p4 = *(const float4*)&qpos[off];
                float4 o;
                o.x = a[0] * inv + sh + t4.x + p4.x;
                o.y = a[1] * inv + sh + t4.y + p4.y;
                o.z = a[2] * inv + sh + t4.z + p4.z;
                o.w = a[3] * inv + sh + t4.w + p4.w;
                *(float4*)&outf[off] = o;
            }
        }
    }
}

extern "C" void kernel_launch(void* const* d_in, const int* in_sizes, int n_in,
                              void* d_out, int out_size, void* d_ws, size_t ws_size,
                              hipStream_t stream) {
    const float* query = (const float*)d_in[0];
    const float* qpos  = (const float*)d_in[3];
    const float* convw = (const float*)d_in[4];
    const float* convb = (const float*)d_in[5];
    const float* gam   = (const float*)d_in[6];
    const float* bet   = (const float*)d_in[7];
    const float* mn    = (const float*)d_in[8];
    const float* vr    = (const float*)d_in[9];
    float* out = (float*)d_out;

    char* ws = (char*)d_ws;
    unsigned short* sxT = (unsigned short*)ws;                  // 4 MB
    unsigned short* sqT = sxT + TOT;                            // 4 MB
    float* kvt = (float*)(sqT + TOT);                           // 256 KB
    unsigned short* whl = (unsigned short*)((char*)kvt + 8 * 8 * 1024 * 4);
    float* bninv = (float*)(whl + 4 * 256 * 512);
    float* bnsh = bninv + 1024;

    prep_spike_kernel<<<512, 256, 0, stream>>>(
        query, qpos, convw, convb, gam, bet, mn, vr, sxT, whl, bninv, bnsh, kvt);
    conv_qkv_kernel<<<512, 256, 0, stream>>>(whl, sxT, bninv, bnsh, sqT, kvt);
    ov_conv_kernel<<<512, 256, 0, stream>>>(
        whl, sqT, kvt, bninv, bnsh, query, qpos, out);
}

// Round 16
// 32.008 us; speedup vs baseline: 1.0410x; 1.0410x over previous
//
#include <hip/hip_runtime.h>
#include <hip/hip_bf16.h>
#include <math.h>

#define N_DIM 1024
#define C_DIM 256
#define CN (C_DIM * N_DIM)
#define TOT (8 * CN)
#define BN_EPS 1e-5f
#define SCALE 0.1f

typedef short short8 __attribute__((ext_vector_type(8)));
typedef float f32x4 __attribute__((ext_vector_type(4)));

__device__ __forceinline__ float mspike(float x) {
    return rintf(fminf(fmaxf(x, 0.f), 4.f)) * 0.25f;
}
__device__ __forceinline__ unsigned short bfbits(float x) {
    __hip_bfloat16 h = __float2bfloat16(x);
    return *reinterpret_cast<unsigned short*>(&h);
}
__device__ __forceinline__ f32x4 mfma16(short8 a, short8 b, f32x4 c) {
    return __builtin_amdgcn_mfma_f32_16x16x32_bf16(a, b, c, 0, 0, 0);
}
__device__ __forceinline__ void async16(void* lds, const void* g) {
    __builtin_amdgcn_global_load_lds(
        (const __attribute__((address_space(1))) void*)g,
        (__attribute__((address_space(3))) void*)lds, 16, 0, 0);
}

// ==== K1 (512 blocks): add+spike+transpose + 2 weight rows + zero kvt ======
__global__ __launch_bounds__(256) void prep_spike_kernel(
    const float* __restrict__ q, const float* __restrict__ qp,
    const float* __restrict__ w, const float* __restrict__ cb,
    const float* __restrict__ g, const float* __restrict__ bet,
    const float* __restrict__ mn, const float* __restrict__ vr,
    unsigned short* __restrict__ sxT, unsigned short* __restrict__ whl,
    float* __restrict__ bninv, float* __restrict__ bnsh,
    float* __restrict__ kvt) {
    int logical = ((blockIdx.x & 7) << 6) + (blockIdx.x >> 3);
    int t = threadIdx.x;
    if (blockIdx.x < 64) {
        float4 z4 = make_float4(0.f, 0.f, 0.f, 0.f);
        ((float4*)kvt)[blockIdx.x * 256 + t] = z4;
    }
    __shared__ float ld[64][65];
    {
        int tb = logical >> 6, u = logical & 63;
        int c0 = (u >> 4) * 64, n0 = (u & 15) * 64;
        int cl = t >> 4, nl = (t & 15) * 4;
        size_t base = (size_t)tb * CN;
#pragma unroll
        for (int r = 0; r < 4; ++r) {
            int c = cl + r * 16;
            size_t off = base + (size_t)(c0 + c) * N_DIM + n0 + nl;
            float4 a = *(const float4*)&q[off];
            float4 b = *(const float4*)&qp[off];
            ld[c][nl] = mspike(a.x + b.x);
            ld[c][nl + 1] = mspike(a.y + b.y);
            ld[c][nl + 2] = mspike(a.z + b.z);
            ld[c][nl + 3] = mspike(a.w + b.w);
        }
        __syncthreads();
        int nl2 = t >> 2, cg2 = (t & 3) * 16;
        size_t ob = base + (size_t)(n0 + nl2) * C_DIM + c0 + cg2;
        short8 v0, v1;
#pragma unroll
        for (int j = 0; j < 8; ++j) {
            v0[j] = (short)bfbits(ld[cg2 + j][nl2]);
            v1[j] = (short)bfbits(ld[cg2 + 8 + j][nl2]);
        }
        *(short8*)&sxT[ob] = v0;
        *(short8*)&sxT[ob + 8] = v1;
    }
    {
        int row = 2 * logical + (t >> 7);
        int tl = t & 127;
        float2 wv = *(const float2*)&w[(size_t)row * 256 + tl * 2];
        __hip_bfloat16 h0 = __float2bfloat16(wv.x);
        __hip_bfloat16 h1 = __float2bfloat16(wv.y);
        __hip_bfloat16 l0 = __float2bfloat16(wv.x - __bfloat162float(h0));
        __hip_bfloat16 l1 = __float2bfloat16(wv.y - __bfloat162float(h1));
        size_t base = (size_t)row * 512;
        *(ushort2*)&whl[base + tl * 2] =
            make_ushort2(*(unsigned short*)&h0, *(unsigned short*)&h1);
        *(ushort2*)&whl[base + 256 + tl * 2] =
            make_ushort2(*(unsigned short*)&l0, *(unsigned short*)&l1);
        if (tl == 0) {
            float inv = g[row] / sqrtf(vr[row] + BN_EPS);
            bninv[row] = inv;
            bnsh[row] = (cb[row] - mn[row]) * inv + bet[row];
        }
    }
}

// ==== K2 (512 blocks): q conv (u<32) | fused kv conv + kTv f32 atomics =====
__global__ __launch_bounds__(256, 2) void conv_qkv_kernel(
    const unsigned short* __restrict__ whl,
    const unsigned short* __restrict__ actT,
    const float* __restrict__ bninv, const float* __restrict__ bnsh,
    unsigned short* __restrict__ dq, float* __restrict__ kvt) {
    __shared__ char lds[49152];
    int bz = blockIdx.x;
    int tb = bz & 7, u = bz >> 3;
    const int tid = threadIdx.x, lane = tid & 63, wid = tid >> 6;
    const int wm = wid >> 1, wn = wid & 1;
    const int l15 = lane & 15, l4 = lane >> 4;
    const unsigned short* abase = actT + (size_t)tb * CN;
    f32x4 z = {0.f, 0.f, 0.f, 0.f};

    if (u < 32) {
        int m0 = (u >> 4) * 128, n0 = (u & 15) * 64;
        short* Bp = (short*)lds;
        short* Aq = (short*)(lds + 32768);
        const unsigned short* pa[4];
        const unsigned short* pb[2];
#pragma unroll
        for (int c = 0; c < 4; ++c) {
            int s = c * 256 + tid, row = s >> 3, gsw = ((s & 7) ^ (row & 7)) * 8;
            pa[c] = whl + (size_t)(m0 + row) * 512 + gsw;
        }
#pragma unroll
        for (int c = 0; c < 2; ++c) {
            int s = c * 256 + tid, row = s >> 3, gsw = ((s & 7) ^ (row & 7)) * 8;
            pb[c] = abase + (size_t)(n0 + row) * 256 + gsw;
        }
        f32x4 acc[4][2];
#pragma unroll
        for (int i = 0; i < 4; ++i) { acc[i][0] = z; acc[i][1] = z; }
#pragma unroll
        for (int p = 0; p < 4; ++p)
#pragma unroll
            for (int c = 0; c < 2; ++c)
                async16(&Bp[p * 4096 + (c * 256 + tid) * 8], pb[c] + p * 64);
#pragma unroll
        for (int c = 0; c < 4; ++c)
            async16(&Aq[(c * 256 + tid) * 8], pa[c]);
        __syncthreads();
        for (int kt = 0; kt < 8; ++kt) {
            const char* bbase = (const char*)(Bp + (kt & 3) * 4096);
#pragma unroll
            for (int kk = 0; kk < 2; ++kk) {
                short8 af[4], bf[2];
#pragma unroll
                for (int f = 0; f < 4; ++f) {
                    int rowa = wm * 64 + f * 16 + l15;
                    int ka = ((kk * 4 + l4) ^ (rowa & 7)) << 4;
                    af[f] = *(const short8*)((const char*)Aq + rowa * 128 + ka);
                }
#pragma unroll
                for (int f = 0; f < 2; ++f) {
                    int rowb = wn * 32 + f * 16 + l15;
                    int kb2 = ((kk * 4 + l4) ^ (rowb & 7)) << 4;
                    bf[f] = *(const short8*)(bbase + rowb * 128 + kb2);
                }
#pragma unroll
                for (int i = 0; i < 4; ++i) {
                    acc[i][0] = mfma16(af[i], bf[0], acc[i][0]);
                    acc[i][1] = mfma16(af[i], bf[1], acc[i][1]);
                }
            }
            __syncthreads();
            if (kt < 7) {
#pragma unroll
                for (int c = 0; c < 4; ++c)
                    async16(&Aq[(c * 256 + tid) * 8], pa[c] + (kt + 1) * 64);
                __syncthreads();
            }
        }
#pragma unroll
        for (int i = 0; i < 4; ++i) {
            int cb4 = m0 + wm * 64 + i * 16 + l4 * 4;
            float4 inv = *(const float4*)&bninv[cb4];
            float4 sh = *(const float4*)&bnsh[cb4];
#pragma unroll
            for (int j = 0; j < 2; ++j) {
                int n = n0 + wn * 32 + j * 16 + l15;
                f32x4 a = acc[i][j];
                ushort4 u4;
                u4.x = bfbits(mspike(a[0] * inv.x + sh.x));
                u4.y = bfbits(mspike(a[1] * inv.y + sh.y));
                u4.z = bfbits(mspike(a[2] * inv.z + sh.z));
                u4.w = bfbits(mspike(a[3] * inv.w + sh.w));
                *(ushort4*)&dq[(size_t)tb * CN + (size_t)n * C_DIM + cb4] = u4;
            }
        }
    } else {
        int v = u - 32;
        int m0 = (v >> 2) * 128, c0t = v & 3, n0 = c0t * 64;
        short* At = (short*)lds;
        char* Bb = lds + 16384;
        const unsigned short* pa[4];
        const unsigned short* pw[4][2];
#pragma unroll
        for (int c = 0; c < 4; ++c) {
            int s = c * 256 + tid, row = s >> 3, gsw = ((s & 7) ^ (row & 7)) * 8;
            pa[c] = abase + (size_t)(m0 + row) * 256 + gsw;
        }
#pragma unroll
        for (int c = 0; c < 2; ++c) {
            int s = c * 256 + tid, row = s >> 3, gsw = ((s & 7) ^ (row & 7)) * 8;
            const unsigned short* k_base = whl + 131072 + (size_t)(n0 + row) * 512 + gsw;
            const unsigned short* v_base = whl + 2 * 131072 + (size_t)(n0 + row) * 512 + gsw;
            pw[0][c] = k_base;
            pw[1][c] = k_base + 256;
            pw[2][c] = v_base;
            pw[3][c] = v_base + 256;
        }
        f32x4 kacc[4][2], vacc[4][2];
#pragma unroll
        for (int i = 0; i < 4; ++i) {
            kacc[i][0] = z; kacc[i][1] = z; vacc[i][0] = z; vacc[i][1] = z;
        }
        for (int p = 0; p < 4; ++p) {
#pragma unroll
            for (int c = 0; c < 4; ++c)
                async16(&At[(c * 256 + tid) * 8], pa[c] + p * 64);
#pragma unroll
            for (int b = 0; b < 4; ++b)
#pragma unroll
                for (int c = 0; c < 2; ++c)
                    async16(Bb + b * 8192 + (c * 256 + tid) * 16, pw[b][c] + p * 64);
            __syncthreads();
#pragma unroll
            for (int kk = 0; kk < 2; ++kk) {
                short8 af[4];
#pragma unroll
                for (int f = 0; f < 4; ++f) {
                    int rowa = wm * 64 + f * 16 + l15;
                    int ka = ((kk * 4 + l4) ^ (rowa & 7)) << 4;
                    af[f] = *(const short8*)((const char*)At + rowa * 128 + ka);
                }
                short8 bf[4][2];
#pragma unroll
                for (int b = 0; b < 4; ++b)
#pragma unroll
                    for (int f = 0; f < 2; ++f) {
                        int rowb = wn * 32 + f * 16 + l15;
                        int kb2 = ((kk * 4 + l4) ^ (rowb & 7)) << 4;
                        bf[b][f] = *(const short8*)(Bb + b * 8192 + rowb * 128 + kb2);
                    }
#pragma unroll
                for (int i = 0; i < 4; ++i) {
#pragma unroll
                    for (int f = 0; f < 2; ++f) {
                        kacc[i][f] = mfma16(af[i], bf[0][f], kacc[i][f]);
                        kacc[i][f] = mfma16(af[i], bf[1][f], kacc[i][f]);
                        vacc[i][f] = mfma16(af[i], bf[2][f], vacc[i][f]);
                        vacc[i][f] = mfma16(af[i], bf[3][f], vacc[i][f]);
                    }
                }
            }
            __syncthreads();
        }
        char* kT = lds;
        char* vT = lds + 17408;
#pragma unroll
        for (int j = 0; j < 2; ++j) {
            int cwi = wn * 32 + j * 16 + l15;
            int ck = 256 + n0 + cwi;
            int cv = 512 + n0 + cwi;
            float kinv = bninv[ck], ksh = bnsh[ck];
            float vinv = bninv[cv], vsh = bnsh[cv];
#pragma unroll
            for (int i = 0; i < 4; ++i) {
                int nb = wm * 64 + i * 16 + l4 * 4;
                f32x4 ka = kacc[i][j], va = vacc[i][j];
                ushort4 ku, vu;
                ku.x = bfbits(mspike(ka[0] * kinv + ksh));
                ku.y = bfbits(mspike(ka[1] * kinv + ksh));
                ku.z = bfbits(mspike(ka[2] * kinv + ksh));
                ku.w = bfbits(mspike(ka[3] * kinv + ksh));
                vu.x = bfbits(mspike(va[0] * vinv + vsh));
                vu.y = bfbits(mspike(va[1] * vinv + vsh));
                vu.z = bfbits(mspike(va[2] * vinv + vsh));
                vu.w = bfbits(mspike(va[3] * vinv + vsh));
                *(ushort4*)(kT + cwi * 272 + nb * 2) = ku;
                *(ushort4*)(vT + cwi * 272 + nb * 2) = vu;
            }
        }
        __syncthreads();
        f32x4 pk[2];
        pk[0] = z; pk[1] = z;
#pragma unroll
        for (int ks = 0; ks < 4; ++ks) {
            short8 a = *(const short8*)(vT + (wn * 32 + wm * 16 + l15) * 272 +
                                        ks * 64 + l4 * 16);
#pragma unroll
            for (int j = 0; j < 2; ++j) {
                short8 b = *(const short8*)(kT + (wn * 32 + j * 16 + l15) * 272 +
                                            ks * 64 + l4 * 16);
                pk[j] = mfma16(a, b, pk[j]);
            }
        }
        int h = c0t * 2 + wn;
        float* dst = kvt + (((size_t)tb * 8 + h) * 32) * 32;
#pragma unroll
        for (int j = 0; j < 2; ++j)
#pragma unroll
            for (int r = 0; r < 4; ++r) {
                int d2 = wm * 16 + l4 * 4 + r, d1 = j * 16 + l15;
                atomicAdd(&dst[(size_t)d2 * 32 + d1], pk[j][r]);
            }
    }
}

// ==== K3 (256 blocks): kvt hi/lo split + ov + final conv + residual ========
__global__ __launch_bounds__(256, 2) void ov_conv_kernel(
    const unsigned short* __restrict__ whl,
    const unsigned short* __restrict__ sqT,
    const float* __restrict__ kvtg,
    const float* __restrict__ bninv, const float* __restrict__ bnsh,
    const float* __restrict__ query, const float* __restrict__ qpos,
    float* __restrict__ outf) {
    __shared__ char lds[65536];
    char* kvt = lds;
    char* oT = lds + 32768;
    int bz = blockIdx.x;
    int tb = bz & 7, u = bz >> 3;
    int m0 = (u >> 1) * 64, cop = u & 1;
    const int tid = threadIdx.x, lane = tid & 63, w = tid >> 6;
    const int l15 = lane & 15, l4 = lane >> 4;
    f32x4 z = {0.f, 0.f, 0.f, 0.f};

    // phase A: read exact kTv, hi/lo split -> kvt[h*32+d2][d1 hi|lo]
    {
        int h = tid >> 5, d2 = tid & 31;
        const float* src = kvtg + (((size_t)tb * 8 + h) * 32 + d2) * 32;
        unsigned short hl[64];
#pragma unroll
        for (int c = 0; c < 8; ++c) {
            float4 v4 = *(const float4*)&src[c * 4];
            float xs[4] = {v4.x, v4.y, v4.z, v4.w};
#pragma unroll
            for (int e = 0; e < 4; ++e) {
                int d = c * 4 + e;
                unsigned short hi = bfbits(xs[e]);
                __hip_bfloat16 hb = *(__hip_bfloat16*)&hi;
                hl[d] = hi;
                hl[32 + d] = bfbits(xs[e] - __bfloat162float(hb));
            }
        }
        int row = tid;
#pragma unroll
        for (int c = 0; c < 8; ++c) {
            short8 v8;
#pragma unroll
            for (int e = 0; e < 8; ++e) v8[e] = (short)hl[c * 8 + e];
            *(short8*)(kvt + row * 128 + ((c * 16) ^ ((row & 7) << 4))) = v8;
        }
    }
    __syncthreads();

    // phase B: o rows n = m0 + w*16 + ..., all 256 c -> spiked oT
    {
        f32x4 oacc[8][2];
#pragma unroll
        for (int h = 0; h < 8; ++h) { oacc[h][0] = z; oacc[h][1] = z; }
        const unsigned short* qb = sqT + (size_t)tb * CN;
#pragma unroll
        for (int h = 0; h < 8; ++h) {
            int n = m0 + w * 16 + l15;
            short8 aq = *(const short8*)&qb[(size_t)n * C_DIM + h * 32 + l4 * 8];
#pragma unroll
            for (int j = 0; j < 2; ++j) {
                int row = h * 32 + j * 16 + l15;
                short8 bhi = *(const short8*)(kvt + row * 128 +
                                              ((l4 * 16) ^ ((row & 7) << 4)));
                short8 blo = *(const short8*)(kvt + row * 128 +
                                              ((64 + l4 * 16) ^ ((row & 7) << 4)));
                oacc[h][j] = mfma16(aq, bhi, oacc[h][j]);
                oacc[h][j] = mfma16(aq, blo, oacc[h][j]);
            }
        }
#pragma unroll
        for (int h = 0; h < 8; ++h)
#pragma unroll
            for (int j = 0; j < 2; ++j)
#pragma unroll
                for (int r = 0; r < 4; ++r) {
                    int n = w * 16 + l4 * 4 + r;
                    int c = h * 32 + j * 16 + l15;
                    unsigned short sv = bfbits(mspike(SCALE * oacc[h][j][r]));
                    *(unsigned short*)(oT + n * 512 +
                                       ((c * 2) ^ ((n & 7) << 4))) = sv;
                }
    }
    __syncthreads();

    // phase C: out = o @ W3hi^T + BN + (query+qpos) residual
    {
        f32x4 acc[4][2];
#pragma unroll
        for (int i = 0; i < 4; ++i) { acc[i][0] = z; acc[i][1] = z; }
        const unsigned short* w3 = whl + 3 * 131072;
#pragma unroll
        for (int kc = 0; kc < 8; ++kc) {
            short8 af[4], bf[2];
#pragma unroll
            for (int i = 0; i < 4; ++i) {
                int n = i * 16 + l15;
                af[i] = *(const short8*)(oT + n * 512 +
                                         ((kc * 64 + l4 * 16) ^ ((n & 7) << 4)));
            }
#pragma unroll
            for (int j = 0; j < 2; ++j) {
                int crow = cop * 128 + (w * 2 + j) * 16 + l15;
                bf[j] = *(const short8*)&w3[(size_t)crow * 512 + kc * 32 + l4 * 8];
            }
#pragma unroll
            for (int i = 0; i < 4; ++i) {
                acc[i][0] = mfma16(af[i], bf[0], acc[i][0]);
                acc[i][1] = mfma16(af[i], bf[1], acc[i][1]);
            }
        }
#pragma unroll
        for (int j = 0; j < 2; ++j) {
            int c = cop * 128 + (w * 2 + j) * 16 + l15;
            float inv = bninv[768 + c], sh = bnsh[768 + c];
#pragma unroll
            for (int i = 0; i < 4; ++i) {
                int nb = m0 + i * 16 + l4 * 4;
                size_t off = (size_t)tb * CN + (size_t)c * N_DIM + nb;
                f32x4 a = acc[i][j];
                float4 t4 = *(const float4*)&query[off];
                float4 p4 = *(const float4*)&qpos[off];
                float4 o;
                o.x = a[0] * inv + sh + t4.x + p4.x;
                o.y = a[1] * inv + sh + t4.y + p4.y;
                o.z = a[2] * inv + sh + t4.z + p4.z;
                o.w = a[3] * inv + sh + t4.w + p4.w;
                *(float4*)&outf[off] = o;
            }
        }
    }
}

extern "C" void kernel_launch(void* const* d_in, const int* in_sizes, int n_in,
                              void* d_out, int out_size, void* d_ws, size_t ws_size,
                              hipStream_t stream) {
    const float* query = (const float*)d_in[0];
    const float* qpos  = (const float*)d_in[3];
    const float* convw = (const float*)d_in[4];
    const float* convb = (const float*)d_in[5];
    const float* gam   = (const float*)d_in[6];
    const float* bet   = (const float*)d_in[7];
    const float* mn    = (const float*)d_in[8];
    const float* vr    = (const float*)d_in[9];
    float* out = (float*)d_out;

    char* ws = (char*)d_ws;
    unsigned short* sxT = (unsigned short*)ws;                  // 4 MB
    unsigned short* sqT = sxT + TOT;                            // 4 MB
    float* kvt = (float*)(sqT + TOT);                           // 256 KB
    unsigned short* whl = (unsigned short*)((char*)kvt + 8 * 8 * 1024 * 4);
    float* bninv = (float*)(whl + 4 * 256 * 512);
    float* bnsh = bninv + 1024;

    prep_spike_kernel<<<512, 256, 0, stream>>>(
        query, qpos, convw, convb, gam, bet, mn, vr, sxT, whl, bninv, bnsh, kvt);
    conv_qkv_kernel<<<512, 256, 0, stream>>>(whl, sxT, bninv, bnsh, sqT, kvt);
    ov_conv_kernel<<<256, 256, 0, stream>>>(
        whl, sqT, kvt, bninv, bnsh, query, qpos, out);
}